// Round 19
// baseline (173.172 us; speedup 1.0000x reference)
//
#include <hip/hip_runtime.h>
#include <hip/hip_bf16.h>
#include <stdint.h>

// GQA attention block, MI355X gfx950.
// R1-R4: attention ladder (swapped-QK^T, in-reg softmax, LDS-staged K/V, swizzle).
// R5-R7: GEMM schedule experiments (null); RoPE fused into QKV GEMM.
// R8: m97 128x128 GEMM shape. R9: vectorized transposes; LDS-bounce epilogue.
// R11: attn 64 q-rows/wave. R13: out-proj 512-thr (16 waves/CU).
// R16: Vt fused into QKV V-epilogue. R17: merged k_prep (168.7 us).
// R18: out-proj -> 128x64 tiles, grid 1024, 4 blocks/CU (more barrier groups);
//      attn blocks XCD-affine (g = bid&7) so each XCD L2-caches its K/V.

typedef __attribute__((ext_vector_type(4))) float f32x4;
typedef __attribute__((ext_vector_type(16))) float f32x16;
typedef __attribute__((ext_vector_type(8))) short sfrag;   // 8 bf16 bits
typedef __attribute__((ext_vector_type(8))) __bf16 bfrag;
typedef __attribute__((ext_vector_type(4))) unsigned int u32x4;
typedef unsigned short u16;

__device__ __forceinline__ f32x4 mfma16(sfrag a, sfrag b, f32x4 c) {
  return __builtin_amdgcn_mfma_f32_16x16x32_bf16(
      __builtin_bit_cast(bfrag, a), __builtin_bit_cast(bfrag, b), c, 0, 0, 0);
}
__device__ __forceinline__ f32x16 mfma32(sfrag a, sfrag b, f32x16 c) {
  return __builtin_amdgcn_mfma_f32_32x32x16_bf16(
      __builtin_bit_cast(bfrag, a), __builtin_bit_cast(bfrag, b), c, 0, 0, 0);
}
__device__ __forceinline__ u16 f2b(float f) {
  return __builtin_bit_cast(u16, (__bf16)f);
}
__device__ __forceinline__ unsigned pack2(float a, float b) {
  return (unsigned)f2b(a) | ((unsigned)f2b(b) << 16);
}
// a' = [a(0:31)|b(0:31)], b' = [a(32:63)|b(32:63)]
__device__ __forceinline__ void swap32(unsigned& a, unsigned& b) {
  asm("v_permlane32_swap_b32 %0, %1" : "+v"(a), "+v"(b));
}

#define GAS __attribute__((address_space(1)))
#define LAS __attribute__((address_space(3)))
__device__ __forceinline__ void gll16(const void* g, void* l) {
  __builtin_amdgcn_global_load_lds((GAS unsigned int*)g, (LAS unsigned int*)l, 16, 0, 0);
}

// ---------- merged prep ----------
// bid 0..2559: weight transposes; 2560..10751: x f32->bf16; 10752..11007: csn.
__global__ __launch_bounds__(256) void k_prep(const float* __restrict__ X,
                                              u16* __restrict__ Y,
                                              const int* __restrict__ sp,
                                              float2* __restrict__ csn,
                                              const float* __restrict__ Wq,
                                              const float* __restrict__ Wk,
                                              const float* __restrict__ Wv,
                                              const float* __restrict__ Wo,
                                              u16* __restrict__ Wqkvt,
                                              u16* __restrict__ Wot) {
  __shared__ float tile[64][65];
  const int bid = blockIdx.x;
  const int tid = threadIdx.x;
  if (bid < 2560) {                       // ---- weight transpose ----
    const int bx = bid % 80;
    const int k0 = (bid / 80) * 64;
    const float* W; int N, n0; u16* Dst; int nd;
    if (bx < 32)      { W = Wq; N = 2048; n0 = bx * 64;        Dst = Wqkvt; nd = n0; }
    else if (bx < 40) { W = Wk; N = 512;  n0 = (bx - 32) * 64; Dst = Wqkvt; nd = 2048 + n0; }
    else if (bx < 48) { W = Wv; N = 512;  n0 = (bx - 40) * 64; Dst = Wqkvt; nd = 2560 + n0; }
    else              { W = Wo; N = 2048; n0 = (bx - 48) * 64; Dst = Wot;   nd = n0; }
    #pragma unroll
    for (int it = 0; it < 4; ++it) {
      const int idx = it * 256 + tid;          // 0..1023
      const int kk = idx >> 4, nq = idx & 15;
      float4 v = *(const float4*)(W + (size_t)(k0 + kk) * N + n0 + nq * 4);
      tile[kk][nq * 4 + 0] = v.x;
      tile[kk][nq * 4 + 1] = v.y;
      tile[kk][nq * 4 + 2] = v.z;
      tile[kk][nq * 4 + 3] = v.w;
    }
    __syncthreads();
    #pragma unroll
    for (int it = 0; it < 4; ++it) {
      const int idx = it * 256 + tid;
      const int nn = idx >> 4, kq = idx & 15;
      ushort4 o;
      o.x = f2b(tile[kq * 4 + 0][nn]);
      o.y = f2b(tile[kq * 4 + 1][nn]);
      o.z = f2b(tile[kq * 4 + 2][nn]);
      o.w = f2b(tile[kq * 4 + 3][nn]);
      *(ushort4*)(Dst + (size_t)(nd + nn) * 2048 + k0 + kq * 4) = o;
    }
  } else if (bid < 10752) {               // ---- x f32 -> bf16 ----
    const int i = ((bid - 2560) * 256 + tid) * 4;
    float4 v = *(const float4*)(X + i);
    *(ushort4*)(Y + i) = make_ushort4(f2b(v.x), f2b(v.y), f2b(v.z), f2b(v.w));
  } else {                                // ---- cos/sin table ----
    const int i = (bid - 10752) * 256 + tid;   // 65536 = 2048 x 32
    const int t = i >> 5, j = i & 31;
    const float freq = powf(10000.0f, -(float)j * (1.0f / 32.0f));
    const float ang = (float)(sp[0] + t) * freq;
    csn[i] = make_float2(cosf(ang), sinf(ang));
  }
}

// ---------- QKV GEMM 128x128/BK=64, 4 waves, single-buffer m97 structure ----------
// Fused RoPE epilogue; wave's 64 cols = head bx*2+wn; Q/K bf16 via LDS bounce.
// V branch: Vout f32 direct + Vt bf16 (B,G,hd,T) via XOR-swizzled LDS transpose.
__global__ __launch_bounds__(256, 3) void k_gemmQKV(const u16* __restrict__ A,
                                                    const u16* __restrict__ Bt,
                                                    int K, int GY,
                                                    const float2* __restrict__ csn,
                                                    u16* __restrict__ Qb,
                                                    u16* __restrict__ Kb,
                                                    float* __restrict__ Kout,
                                                    float* __restrict__ Vout,
                                                    u16* __restrict__ Vt) {
  __shared__ u16 lds[16384];                    // 32 KB
  char* const L = (char*)&lds[0];
  const int tid = threadIdx.x;
  const int q8 = gridDim.x >> 3;                // 768 % 8 == 0 (bijective)
  const int id2 = (blockIdx.x & 7) * q8 + (blockIdx.x >> 3);
  const int by = id2 % GY, bx = id2 / GY;
  const int wid = tid >> 6, lane = tid & 63;
  const int wm = wid >> 1, wn = wid & 1;        // 2 x 2 waves, 64x64 C each
  const int l16 = lane & 15, l4 = lane >> 4;
  const size_t K2 = (size_t)K * 2;
  const char* Ab = (const char*)(A + (size_t)(by * 128) * K);
  const char* Bb = (const char*)(Bt + (size_t)(bx * 128) * K);
  const int NT = K >> 6;

  auto stage = [&](const char* gb, int reg, int t) {
    #pragma unroll
    for (int ld = 0; ld < 4; ++ld) {
      const int p = ld * 4096 + tid * 16;
      const int r = p >> 7;
      const int cb = (p & 127) ^ ((r & 7) << 4);
      gll16(gb + (size_t)r * K2 + (size_t)t * 128 + cb, L + reg + p);
    }
  };

  const int swz = (l16 & 7) << 4;
  const int c0 = (l4 * 16) ^ swz;               // k-half 0
  const int c1 = (64 + l4 * 16) ^ swz;          // k-half 1
  const int aOff = (wm * 64 + l16) * 128;
  const int bOff = 16384 + (wn * 64 + l16) * 128;

  f32x4 acc[4][4];
  #pragma unroll
  for (int m = 0; m < 4; ++m)
    #pragma unroll
    for (int n = 0; n < 4; ++n) acc[m][n] = f32x4{0.f, 0.f, 0.f, 0.f};

  for (int t = 0; t < NT; ++t) {
    stage(Ab, 0, t);
    stage(Bb, 16384, t);
    __syncthreads();                            // drains vmcnt -> staged data visible
    sfrag a0[4], a1[4], b0[4], b1[4];
    #pragma unroll
    for (int m = 0; m < 4; ++m) {
      a0[m] = *(const sfrag*)(L + aOff + m * 2048 + c0);
      a1[m] = *(const sfrag*)(L + aOff + m * 2048 + c1);
    }
    #pragma unroll
    for (int n = 0; n < 4; ++n) {
      b0[n] = *(const sfrag*)(L + bOff + n * 2048 + c0);
      b1[n] = *(const sfrag*)(L + bOff + n * 2048 + c1);
    }
    #pragma unroll
    for (int m = 0; m < 4; ++m)
      #pragma unroll
      for (int n = 0; n < 4; ++n) {
        acc[m][n] = mfma16(a0[m], b0[n], acc[m][n]);
        acc[m][n] = mfma16(a1[m], b1[n], acc[m][n]);
      }
    __syncthreads();                            // protect buffer overwrite
  }

  const int head = bx * 2 + wn;
  const int row0 = by * 128 + wm * 64;
  if (head < 40) {                    // Q (0..31) or K (32..39): rope + LDS bounce
    u16* Lw = (u16*)(L + wid * 8192);          // this wave's 64x64 bf16 tile
    const float QS = 0.125f * 1.44269504f;     // 1/sqrt(hd) * log2(e)
    const bool isQ = head < 32;
    #pragma unroll
    for (int m = 0; m < 4; ++m)
      #pragma unroll
      for (int r = 0; r < 4; ++r) {
        const int tl = m * 16 + l4 * 4 + r;
        const int tg = row0 + tl;
        const int b = tg >> 11, t = tg & 2047;
        #pragma unroll
        for (int n = 0; n < 2; ++n) {
          const int j = n * 16 + l16;
          const float2 cz = csn[t * 32 + j];
          const float x1 = acc[m][n][r], x2 = acc[m][n + 2][r];
          const float o1 = x1 * cz.x - x2 * cz.y;
          const float o2 = x1 * cz.y + x2 * cz.x;
          if (isQ) {
            Lw[tl * 64 + j]      = f2b(o1 * QS);
            Lw[tl * 64 + j + 32] = f2b(o2 * QS);
          } else {
            Lw[tl * 64 + j]      = f2b(o1);
            Lw[tl * 64 + j + 32] = f2b(o2);
            const int g = head - 32;
            const size_t o = (((size_t)b * 8 + g) * 2048 + t) * 64 + j;
            Kout[o] = o1;  Kout[o + 32] = o2;
          }
        }
      }
    __syncthreads();   // block-uniform here (head<40 <=> bx<20); orders LDS w->r
    u16* dst = isQ ? Qb : Kb;
    const int hh = isQ ? head : (head - 32);
    const int hstride = isQ ? 32 : 8;
    #pragma unroll
    for (int it = 0; it < 8; ++it) {
      const int tl = it * 8 + (lane >> 3);
      const int col = (lane & 7) * 8;          // u16 units, 16B chunk
      const u32x4 v = *(const u32x4*)&Lw[tl * 64 + col];
      const int tg = row0 + tl;
      const int b = tg >> 11, t = tg & 2047;
      *(u32x4*)(dst + (((size_t)b * hstride + hh) * 2048 + t) * 64 + col) = v;
    }
  } else {                            // V (40..47): Vout f32 + Vt via LDS transpose
    const int g = head - 40;
    u16* Lw = (u16*)(L + wid * 8192);          // 64(d) x 64(t) u16, col-XOR-swizzled
    #pragma unroll
    for (int m = 0; m < 4; ++m)
      #pragma unroll
      for (int r = 0; r < 4; ++r) {
        const int tl = m * 16 + l4 * 4 + r;    // t index 0..63
        const int tg = row0 + tl;
        const int b = tg >> 11, t = tg & 2047;
        const size_t o = (((size_t)b * 8 + g) * 2048 + t) * 64;
        #pragma unroll
        for (int n = 0; n < 4; ++n) {
          Vout[o + n * 16 + l16] = acc[m][n][r];
          const int d = n * 16 + l16;          // hd index 0..63
          Lw[d * 64 + (tl ^ ((d & 7) << 3))] = f2b(acc[m][n][r]);
        }
      }
    __syncthreads();   // block-uniform (bx 20..23 -> heads 40..47 all V)
    const int bb = row0 >> 11, tt0 = row0 & 2047;   // 64-row tile never crosses b
    #pragma unroll
    for (int it = 0; it < 8; ++it) {
      const int d = it * 8 + (lane >> 3);
      const int toff = (lane & 7) * 8;         // u16 units, 16B chunk
      const u32x4 v = *(const u32x4*)&Lw[d * 64 + (toff ^ ((d & 7) << 3))];
      *(u32x4*)(Vt + (((size_t)bb * 8 + g) * 64 + d) * 2048 + tt0 + toff) = v;
    }
  }
}

// ---------- out-proj GEMM 128x64/BK=64, 256 threads / 4 waves (2x2, 64x32 each) ----
// Grid 1024 (32 by x 32 bx), 24KB LDS -> 4 blocks/CU resident: more independent
// barrier groups per CU to hide the stage/drain (m114 mechanism, R13 precedent).
__global__ __launch_bounds__(256, 4) void k_gemmOut(const u16* __restrict__ A,
                                                    const u16* __restrict__ Bt,
                                                    float* __restrict__ C,
                                                    int N, int K, int GY) {
  __shared__ u16 lds[12288];                    // 24 KB: A 16KB + B 8KB
  char* const L = (char*)&lds[0];
  const int tid = threadIdx.x;
  const int q8 = gridDim.x >> 3;                // 1024 % 8 == 0 (bijective)
  const int id2 = (blockIdx.x & 7) * q8 + (blockIdx.x >> 3);
  const int by = id2 % GY, bx = id2 / GY;       // GY=32; bx in [0,32)
  const int wid = tid >> 6, lane = tid & 63;
  const int wm = wid >> 1, wn = wid & 1;        // 2 x 2 waves, 64x32 C each
  const int l16 = lane & 15, l4 = lane >> 4;
  const size_t K2 = (size_t)K * 2;
  const char* Ab = (const char*)(A + (size_t)(by * 128) * K);
  const char* Bb = (const char*)(Bt + (size_t)(bx * 64) * K);
  const int NT = K >> 6;

  auto stageA = [&](int t) {
    #pragma unroll
    for (int ld = 0; ld < 4; ++ld) {
      const int p = ld * 4096 + tid * 16;       // 0..16383
      const int r = p >> 7;                     // 0..127
      const int cb = (p & 127) ^ ((r & 7) << 4);
      gll16(Ab + (size_t)r * K2 + (size_t)t * 128 + cb, L + p);
    }
  };
  auto stageB = [&](int t) {
    #pragma unroll
    for (int ld = 0; ld < 2; ++ld) {
      const int p = ld * 4096 + tid * 16;       // 0..8191
      const int r = p >> 7;                     // 0..63
      const int cb = (p & 127) ^ ((r & 7) << 4);
      gll16(Bb + (size_t)r * K2 + (size_t)t * 128 + cb, L + 16384 + p);
    }
  };

  const int swz = (l16 & 7) << 4;
  const int c0 = (l4 * 16) ^ swz;               // k-half 0
  const int c1 = (64 + l4 * 16) ^ swz;          // k-half 1
  const int aOff = (wm * 64 + l16) * 128;
  const int bOff = 16384 + (wn * 32 + l16) * 128;

  f32x4 acc[4][2];
  #pragma unroll
  for (int m = 0; m < 4; ++m)
    #pragma unroll
    for (int n = 0; n < 2; ++n) acc[m][n] = f32x4{0.f, 0.f, 0.f, 0.f};

  for (int t = 0; t < NT; ++t) {
    stageA(t);
    stageB(t);
    __syncthreads();
    sfrag a0[4], a1[4], b0[2], b1[2];
    #pragma unroll
    for (int m = 0; m < 4; ++m) {
      a0[m] = *(const sfrag*)(L + aOff + m * 2048 + c0);
      a1[m] = *(const sfrag*)(L + aOff + m * 2048 + c1);
    }
    #pragma unroll
    for (int n = 0; n < 2; ++n) {
      b0[n] = *(const sfrag*)(L + bOff + n * 2048 + c0);
      b1[n] = *(const sfrag*)(L + bOff + n * 2048 + c1);
    }
    #pragma unroll
    for (int m = 0; m < 4; ++m)
      #pragma unroll
      for (int n = 0; n < 2; ++n) {
        acc[m][n] = mfma16(a0[m], b0[n], acc[m][n]);
        acc[m][n] = mfma16(a1[m], b1[n], acc[m][n]);
      }
    __syncthreads();
  }

  float* Cb = C + (size_t)(by * 128 + wm * 64) * N + bx * 64 + wn * 32;
  #pragma unroll
  for (int m = 0; m < 4; ++m)
    #pragma unroll
    for (int n = 0; n < 2; ++n)
      #pragma unroll
      for (int r = 0; r < 4; ++r)
        Cb[(size_t)(m * 16 + l4 * 4 + r) * N + n * 16 + l16] = acc[m][n][r];
}

// ---------- Flash attention v7: attn5 shell, 64 q-rows per wave ----------
__device__ __forceinline__ void pv4(const float* p, sfrag v0a, sfrag v0b,
                                    sfrag v1a, sfrag v1b,
                                    f32x16& O0, f32x16& O1, float& l) {
  unsigned w[8];
  #pragma unroll
  for (int j = 0; j < 8; ++j) w[j] = pack2(p[2 * j], p[2 * j + 1]);
  swap32(w[0], w[2]);
  swap32(w[1], w[3]);
  swap32(w[4], w[6]);
  swap32(w[5], w[7]);
  const sfrag pf0 = __builtin_bit_cast(sfrag, u32x4{w[0], w[1], w[2], w[3]});
  const sfrag pf1 = __builtin_bit_cast(sfrag, u32x4{w[4], w[5], w[6], w[7]});
  O0 = mfma32(v0a, pf0, O0);
  O0 = mfma32(v0b, pf1, O0);
  O1 = mfma32(v1a, pf0, O1);
  O1 = mfma32(v1b, pf1, O1);
  float s[8];
  #pragma unroll
  for (int j = 0; j < 8; ++j) s[j] = p[j] + p[j + 8];
  #pragma unroll
  for (int j = 0; j < 4; ++j) s[j] = s[j] + s[j + 4];
  l += (s[0] + s[1]) + (s[2] + s[3]);
}

__device__ __forceinline__ void tile64_l(const u16* __restrict__ buf,
                                         const sfrag* qf, int hi, int l31, int swz,
                                         f32x16& O0, f32x16& O1, float& l) {
  const char* Kl = (const char*)buf;
  const char* Vl = Kl + 8192;
  const int rb = l31 * 128;
  f32x16 Sa = {}, Sb = {};
  #pragma unroll
  for (int ks = 0; ks < 4; ++ks) {
    const int col = (hi * 16 + ks * 32) ^ swz;
    const sfrag ka = *(const sfrag*)(Kl + rb + col);
    const sfrag kb = *(const sfrag*)(Kl + rb + col + 4096);
    Sa = mfma32(ka, qf[ks], Sa);
    Sb = mfma32(kb, qf[ks], Sb);
  }
  float pa[16], pb[16];
  #pragma unroll
  for (int r = 0; r < 16; ++r) {
    pa[r] = __builtin_amdgcn_exp2f(Sa[r]);
    pb[r] = __builtin_amdgcn_exp2f(Sb[r]);
  }
  sfrag v0[4], v1[4];
  #pragma unroll
  for (int s = 0; s < 4; ++s) {
    const int col = (s * 32 + hi * 16) ^ swz;
    v0[s] = *(const sfrag*)(Vl + rb + col);
    v1[s] = *(const sfrag*)(Vl + rb + col + 4096);
  }
  pv4(pa, v0[0], v0[1], v1[0], v1[1], O0, O1, l);
  pv4(pb, v0[2], v0[3], v1[2], v1[3], O0, O1, l);
}

template<bool MASKED>
__device__ __forceinline__ void tile32_l(const u16* __restrict__ buf, int c,
                                         const sfrag* qf, int hi, int l31, int swz,
                                         f32x16& O0, f32x16& O1, float& l) {
  const char* Kl = (const char*)buf;
  const char* Vl = Kl + 8192;
  const int rb = l31 * 128;
  f32x16 S = {};
  #pragma unroll
  for (int ks = 0; ks < 4; ++ks) {
    const int col = (hi * 16 + ks * 32) ^ swz;
    const sfrag k = *(const sfrag*)(Kl + c * 4096 + rb + col);
    S = mfma32(k, qf[ks], S);
  }
  float p[16];
  #pragma unroll
  for (int r = 0; r < 16; ++r) {
    float s = S[r];
    if (MASKED) {
      int kvo = (r & 3) + 8 * (r >> 2) + 4 * hi;
      if (kvo > l31) s = -__builtin_inff();
    }
    p[r] = __builtin_amdgcn_exp2f(s);
  }
  const int colA = (c * 64 + hi * 16) ^ swz;
  const int colB = (c * 64 + 32 + hi * 16) ^ swz;
  const sfrag v0a = *(const sfrag*)(Vl + rb + colA);
  const sfrag v0b = *(const sfrag*)(Vl + rb + colB);
  const sfrag v1a = *(const sfrag*)(Vl + rb + colA + 4096);
  const sfrag v1b = *(const sfrag*)(Vl + rb + colB + 4096);
  pv4(p, v0a, v0b, v1a, v1b, O0, O1, l);
}

// Block = (qb2, b, g): 4 waves = 4 heads; each wave owns 64 q-rows (two subtiles).
// XCD-affine map: g = bid&7 (dispatch round-robins bid across XCDs, so each XCD
// serves one g-group -> its L2 caches that group's K/V, ~1MB hot per XCD).
__global__ __launch_bounds__(256, 2) void k_attn7(const u16* __restrict__ Qb,
                                                  const u16* __restrict__ Kb,
                                                  const u16* __restrict__ Vt,
                                                  u16* __restrict__ attOut) {
  __shared__ u16 lds[2][8192];
  const int bid = blockIdx.x;                 // 512 blocks
  const int g = bid & 7;                      // XCD-affine
  const int b = (bid >> 3) & 1;
  const int qb2 = 31 - (bid >> 4);            // heavy q-blocks launch first
  const int wave = threadIdx.x >> 6, lane = threadIdx.x & 63;
  const int h = g * 4 + wave;
  const int hi = lane >> 5, l31 = lane & 31;
  const int qrow0 = qb2 * 64;                 // this wave: rows qrow0 .. qrow0+63
  const int swz = (l31 & 7) << 4;

  const u16* Qp0 = Qb + (((size_t)b * 32 + h) * 2048 + qrow0 + l31) * 64 + hi * 8;
  sfrag qf0[4], qf1[4];
  #pragma unroll
  for (int ks = 0; ks < 4; ++ks) {
    qf0[ks] = *(const sfrag*)(Qp0 + ks * 16);
    qf1[ks] = *(const sfrag*)(Qp0 + 32 * 64 + ks * 16);
  }

  const char* Kg = (const char*)(Kb + ((size_t)b * 8 + g) * (2048 * 64));
  const char* Vg = (const char*)(Vt + ((size_t)b * 8 + g) * (64 * 2048));

  auto stage = [&](int bufi, int t) {
    const char* Ktile = Kg + (size_t)t * 8192;
    const char* Vtile = Vg + t * 128;
    #pragma unroll
    for (int rd = 0; rd < 2; ++rd) {
      const int p = rd * 4096 + threadIdx.x * 16;
      const int d = p >> 7;
      const int cb = (p & 127) ^ ((d & 7) << 4);
      const int lbase = rd * 4096 + wave * 1024;
      gll16(Ktile + d * 128 + cb, (char*)&lds[bufi][0] + lbase);
      gll16(Vtile + (size_t)d * 4096 + cb, (char*)&lds[bufi][0] + 8192 + lbase);
    }
  };

  f32x16 O00 = {}, O01 = {}, O10 = {}, O11 = {};
  float ls0 = 0.f, ls1 = 0.f;
  const int nfull = qb2;
  int cur = 0;
  stage(0, 0);
  for (int t = 0; t < nfull; ++t) {
    __syncthreads();
    stage(cur ^ 1, t + 1);
    tile64_l(lds[cur], qf0, hi, l31, swz, O00, O01, ls0);
    tile64_l(lds[cur], qf1, hi, l31, swz, O10, O11, ls1);
    cur ^= 1;
  }
  __syncthreads();
  tile32_l<true >(lds[cur], 0, qf0, hi, l31, swz, O00, O01, ls0);
  tile32_l<false>(lds[cur], 0, qf1, hi, l31, swz, O10, O11, ls1);
  tile32_l<true >(lds[cur], 1, qf1, hi, l31, swz, O10, O11, ls1);

  #pragma unroll
  for (int sb = 0; sb < 2; ++sb) {
    const float lsum = sb ? ls1 : ls0;
    const float ltot = lsum + __shfl_xor(lsum, 32);
    const float inv = 1.0f / ltot;
    const size_t orow = ((size_t)b * 2048 + qrow0 + sb * 32 + l31) * 2048 + h * 64;
    #pragma unroll
    for (int dt = 0; dt < 2; ++dt) {
      const f32x16& O = sb ? (dt ? O11 : O10) : (dt ? O01 : O00);
      #pragma unroll
      for (int k = 0; k < 4; ++k) {
        ushort4 o;
        o.x = f2b(O[4 * k + 0] * inv);
        o.y = f2b(O[4 * k + 1] * inv);
        o.z = f2b(O[4 * k + 2] * inv);
        o.w = f2b(O[4 * k + 3] * inv);
        *(ushort4*)&attOut[orow + dt * 32 + 8 * k + 4 * hi] = o;
      }
    }
  }
}

extern "C" void kernel_launch(void* const* d_in, const int* in_sizes, int n_in,
                              void* d_out, int out_size, void* d_ws, size_t ws_size,
                              hipStream_t stream) {
  const float* x  = (const float*)d_in[0];
  const float* Wq = (const float*)d_in[1];
  const float* Wk = (const float*)d_in[2];
  const float* Wv = (const float*)d_in[3];
  const float* Wo = (const float*)d_in[4];
  const int* sp   = (const int*)d_in[5];
  float* y    = (float*)d_out;            // (B,T,2048) f32
  float* Kout = y + 8388608;              // (B,G,T,64) f32
  float* Vout = y + 10485760;             // (B,G,T,64) f32

  char* ws = (char*)d_ws;
  u16*    xb     = (u16*)(ws + 0);          // 16 MiB (reused as attOut later)
  u16*    Wqkvt  = (u16*)(ws + 16777216);   // 12 MiB  (3072 x 2048 bf16, transposed)
  u16*    Wot    = (u16*)(ws + 29360128);   // 8 MiB
  float2* csn    = (float2*)(ws + 37748736);// 512 KiB (2048 x 32 cos/sin)
  u16*    Qbuf   = (u16*)(ws + 88080384);   // 16 MiB  (B,H,T,hd) bf16, pre-scaled
  u16*    Kbuf   = (u16*)(ws + 104857600);  // 4 MiB   (B,G,T,hd) bf16
  u16*    Vt     = (u16*)(ws + 109051904);  // 4 MiB   (B,G,hd,T) bf16
  u16*    attOut = xb;                      // alias: xb dead after QKV GEMM

  k_prep<<<11008, 256, 0, stream>>>(x, xb, sp, csn, Wq, Wk, Wv, Wo, Wqkvt, Wot);
  k_gemmQKV<<<768, 256, 0, stream>>>(xb, Wqkvt, 2048, 32, csn, Qbuf, Kbuf,
                                     Kout, Vout, Vt);
  k_attn7<<<512, 256, 0, stream>>>(Qbuf, Kbuf, Vt, attOut);
  k_gemmOut<<<1024, 256, 0, stream>>>(attOut, Wot, y, 2048, 2048, 32);
}

// Round 20
// 168.652 us; speedup vs baseline: 1.0268x; 1.0268x over previous
//
#include <hip/hip_runtime.h>
#include <hip/hip_bf16.h>
#include <stdint.h>

// GQA attention block, MI355X gfx950.
// R1-R4: attention ladder (swapped-QK^T, in-reg softmax, LDS-staged K/V, swizzle).
// R5-R7: GEMM schedule experiments (null); RoPE fused into QKV GEMM.
// R8: m97 128x128 GEMM shape. R9: vectorized transposes; LDS-bounce epilogue.
// R11: attn 64 q-rows/wave. R13: out-proj 512-thr (16 waves/CU).
// R16: Vt fused into QKV V-epilogue. R17: merged k_prep -> BEST 168.7 us.
// R18: out-proj 128x64 re-tile + attn XCD remap REGRESSED (traffic +50%) -> reverted.
// R19: exact restore of the R17 configuration.

typedef __attribute__((ext_vector_type(4))) float f32x4;
typedef __attribute__((ext_vector_type(16))) float f32x16;
typedef __attribute__((ext_vector_type(8))) short sfrag;   // 8 bf16 bits
typedef __attribute__((ext_vector_type(8))) __bf16 bfrag;
typedef __attribute__((ext_vector_type(4))) unsigned int u32x4;
typedef unsigned short u16;

__device__ __forceinline__ f32x4 mfma16(sfrag a, sfrag b, f32x4 c) {
  return __builtin_amdgcn_mfma_f32_16x16x32_bf16(
      __builtin_bit_cast(bfrag, a), __builtin_bit_cast(bfrag, b), c, 0, 0, 0);
}
__device__ __forceinline__ f32x16 mfma32(sfrag a, sfrag b, f32x16 c) {
  return __builtin_amdgcn_mfma_f32_32x32x16_bf16(
      __builtin_bit_cast(bfrag, a), __builtin_bit_cast(bfrag, b), c, 0, 0, 0);
}
__device__ __forceinline__ u16 f2b(float f) {
  return __builtin_bit_cast(u16, (__bf16)f);
}
__device__ __forceinline__ unsigned pack2(float a, float b) {
  return (unsigned)f2b(a) | ((unsigned)f2b(b) << 16);
}
// a' = [a(0:31)|b(0:31)], b' = [a(32:63)|b(32:63)]
__device__ __forceinline__ void swap32(unsigned& a, unsigned& b) {
  asm("v_permlane32_swap_b32 %0, %1" : "+v"(a), "+v"(b));
}

#define GAS __attribute__((address_space(1)))
#define LAS __attribute__((address_space(3)))
__device__ __forceinline__ void gll16(const void* g, void* l) {
  __builtin_amdgcn_global_load_lds((GAS unsigned int*)g, (LAS unsigned int*)l, 16, 0, 0);
}

// ---------- merged prep ----------
// bid 0..2559: weight transposes; 2560..10751: x f32->bf16; 10752..11007: csn.
__global__ __launch_bounds__(256) void k_prep(const float* __restrict__ X,
                                              u16* __restrict__ Y,
                                              const int* __restrict__ sp,
                                              float2* __restrict__ csn,
                                              const float* __restrict__ Wq,
                                              const float* __restrict__ Wk,
                                              const float* __restrict__ Wv,
                                              const float* __restrict__ Wo,
                                              u16* __restrict__ Wqkvt,
                                              u16* __restrict__ Wot) {
  __shared__ float tile[64][65];
  const int bid = blockIdx.x;
  const int tid = threadIdx.x;
  if (bid < 2560) {                       // ---- weight transpose ----
    const int bx = bid % 80;
    const int k0 = (bid / 80) * 64;
    const float* W; int N, n0; u16* Dst; int nd;
    if (bx < 32)      { W = Wq; N = 2048; n0 = bx * 64;        Dst = Wqkvt; nd = n0; }
    else if (bx < 40) { W = Wk; N = 512;  n0 = (bx - 32) * 64; Dst = Wqkvt; nd = 2048 + n0; }
    else if (bx < 48) { W = Wv; N = 512;  n0 = (bx - 40) * 64; Dst = Wqkvt; nd = 2560 + n0; }
    else              { W = Wo; N = 2048; n0 = (bx - 48) * 64; Dst = Wot;   nd = n0; }
    #pragma unroll
    for (int it = 0; it < 4; ++it) {
      const int idx = it * 256 + tid;          // 0..1023
      const int kk = idx >> 4, nq = idx & 15;
      float4 v = *(const float4*)(W + (size_t)(k0 + kk) * N + n0 + nq * 4);
      tile[kk][nq * 4 + 0] = v.x;
      tile[kk][nq * 4 + 1] = v.y;
      tile[kk][nq * 4 + 2] = v.z;
      tile[kk][nq * 4 + 3] = v.w;
    }
    __syncthreads();
    #pragma unroll
    for (int it = 0; it < 4; ++it) {
      const int idx = it * 256 + tid;
      const int nn = idx >> 4, kq = idx & 15;
      ushort4 o;
      o.x = f2b(tile[kq * 4 + 0][nn]);
      o.y = f2b(tile[kq * 4 + 1][nn]);
      o.z = f2b(tile[kq * 4 + 2][nn]);
      o.w = f2b(tile[kq * 4 + 3][nn]);
      *(ushort4*)(Dst + (size_t)(nd + nn) * 2048 + k0 + kq * 4) = o;
    }
  } else if (bid < 10752) {               // ---- x f32 -> bf16 ----
    const int i = ((bid - 2560) * 256 + tid) * 4;
    float4 v = *(const float4*)(X + i);
    *(ushort4*)(Y + i) = make_ushort4(f2b(v.x), f2b(v.y), f2b(v.z), f2b(v.w));
  } else {                                // ---- cos/sin table ----
    const int i = (bid - 10752) * 256 + tid;   // 65536 = 2048 x 32
    const int t = i >> 5, j = i & 31;
    const float freq = powf(10000.0f, -(float)j * (1.0f / 32.0f));
    const float ang = (float)(sp[0] + t) * freq;
    csn[i] = make_float2(cosf(ang), sinf(ang));
  }
}

// ---------- QKV GEMM 128x128/BK=64, 4 waves, single-buffer m97 structure ----------
// Fused RoPE epilogue; wave's 64 cols = head bx*2+wn; Q/K bf16 via LDS bounce.
// V branch: Vout f32 direct + Vt bf16 (B,G,hd,T) via XOR-swizzled LDS transpose.
__global__ __launch_bounds__(256, 3) void k_gemmQKV(const u16* __restrict__ A,
                                                    const u16* __restrict__ Bt,
                                                    int K, int GY,
                                                    const float2* __restrict__ csn,
                                                    u16* __restrict__ Qb,
                                                    u16* __restrict__ Kb,
                                                    float* __restrict__ Kout,
                                                    float* __restrict__ Vout,
                                                    u16* __restrict__ Vt) {
  __shared__ u16 lds[16384];                    // 32 KB
  char* const L = (char*)&lds[0];
  const int tid = threadIdx.x;
  const int q8 = gridDim.x >> 3;                // 768 % 8 == 0 (bijective)
  const int id2 = (blockIdx.x & 7) * q8 + (blockIdx.x >> 3);
  const int by = id2 % GY, bx = id2 / GY;
  const int wid = tid >> 6, lane = tid & 63;
  const int wm = wid >> 1, wn = wid & 1;        // 2 x 2 waves, 64x64 C each
  const int l16 = lane & 15, l4 = lane >> 4;
  const size_t K2 = (size_t)K * 2;
  const char* Ab = (const char*)(A + (size_t)(by * 128) * K);
  const char* Bb = (const char*)(Bt + (size_t)(bx * 128) * K);
  const int NT = K >> 6;

  auto stage = [&](const char* gb, int reg, int t) {
    #pragma unroll
    for (int ld = 0; ld < 4; ++ld) {
      const int p = ld * 4096 + tid * 16;
      const int r = p >> 7;
      const int cb = (p & 127) ^ ((r & 7) << 4);
      gll16(gb + (size_t)r * K2 + (size_t)t * 128 + cb, L + reg + p);
    }
  };

  const int swz = (l16 & 7) << 4;
  const int c0 = (l4 * 16) ^ swz;               // k-half 0
  const int c1 = (64 + l4 * 16) ^ swz;          // k-half 1
  const int aOff = (wm * 64 + l16) * 128;
  const int bOff = 16384 + (wn * 64 + l16) * 128;

  f32x4 acc[4][4];
  #pragma unroll
  for (int m = 0; m < 4; ++m)
    #pragma unroll
    for (int n = 0; n < 4; ++n) acc[m][n] = f32x4{0.f, 0.f, 0.f, 0.f};

  for (int t = 0; t < NT; ++t) {
    stage(Ab, 0, t);
    stage(Bb, 16384, t);
    __syncthreads();                            // drains vmcnt -> staged data visible
    sfrag a0[4], a1[4], b0[4], b1[4];
    #pragma unroll
    for (int m = 0; m < 4; ++m) {
      a0[m] = *(const sfrag*)(L + aOff + m * 2048 + c0);
      a1[m] = *(const sfrag*)(L + aOff + m * 2048 + c1);
    }
    #pragma unroll
    for (int n = 0; n < 4; ++n) {
      b0[n] = *(const sfrag*)(L + bOff + n * 2048 + c0);
      b1[n] = *(const sfrag*)(L + bOff + n * 2048 + c1);
    }
    #pragma unroll
    for (int m = 0; m < 4; ++m)
      #pragma unroll
      for (int n = 0; n < 4; ++n) {
        acc[m][n] = mfma16(a0[m], b0[n], acc[m][n]);
        acc[m][n] = mfma16(a1[m], b1[n], acc[m][n]);
      }
    __syncthreads();                            // protect buffer overwrite
  }

  const int head = bx * 2 + wn;
  const int row0 = by * 128 + wm * 64;
  if (head < 40) {                    // Q (0..31) or K (32..39): rope + LDS bounce
    u16* Lw = (u16*)(L + wid * 8192);          // this wave's 64x64 bf16 tile
    const float QS = 0.125f * 1.44269504f;     // 1/sqrt(hd) * log2(e)
    const bool isQ = head < 32;
    #pragma unroll
    for (int m = 0; m < 4; ++m)
      #pragma unroll
      for (int r = 0; r < 4; ++r) {
        const int tl = m * 16 + l4 * 4 + r;
        const int tg = row0 + tl;
        const int b = tg >> 11, t = tg & 2047;
        #pragma unroll
        for (int n = 0; n < 2; ++n) {
          const int j = n * 16 + l16;
          const float2 cz = csn[t * 32 + j];
          const float x1 = acc[m][n][r], x2 = acc[m][n + 2][r];
          const float o1 = x1 * cz.x - x2 * cz.y;
          const float o2 = x1 * cz.y + x2 * cz.x;
          if (isQ) {
            Lw[tl * 64 + j]      = f2b(o1 * QS);
            Lw[tl * 64 + j + 32] = f2b(o2 * QS);
          } else {
            Lw[tl * 64 + j]      = f2b(o1);
            Lw[tl * 64 + j + 32] = f2b(o2);
            const int g = head - 32;
            const size_t o = (((size_t)b * 8 + g) * 2048 + t) * 64 + j;
            Kout[o] = o1;  Kout[o + 32] = o2;
          }
        }
      }
    __syncthreads();   // block-uniform here (head<40 <=> bx<20); orders LDS w->r
    u16* dst = isQ ? Qb : Kb;
    const int hh = isQ ? head : (head - 32);
    const int hstride = isQ ? 32 : 8;
    #pragma unroll
    for (int it = 0; it < 8; ++it) {
      const int tl = it * 8 + (lane >> 3);
      const int col = (lane & 7) * 8;          // u16 units, 16B chunk
      const u32x4 v = *(const u32x4*)&Lw[tl * 64 + col];
      const int tg = row0 + tl;
      const int b = tg >> 11, t = tg & 2047;
      *(u32x4*)(dst + (((size_t)b * hstride + hh) * 2048 + t) * 64 + col) = v;
    }
  } else {                            // V (40..47): Vout f32 + Vt via LDS transpose
    const int g = head - 40;
    u16* Lw = (u16*)(L + wid * 8192);          // 64(d) x 64(t) u16, col-XOR-swizzled
    #pragma unroll
    for (int m = 0; m < 4; ++m)
      #pragma unroll
      for (int r = 0; r < 4; ++r) {
        const int tl = m * 16 + l4 * 4 + r;    // t index 0..63
        const int tg = row0 + tl;
        const int b = tg >> 11, t = tg & 2047;
        const size_t o = (((size_t)b * 8 + g) * 2048 + t) * 64;
        #pragma unroll
        for (int n = 0; n < 4; ++n) {
          Vout[o + n * 16 + l16] = acc[m][n][r];
          const int d = n * 16 + l16;          // hd index 0..63
          Lw[d * 64 + (tl ^ ((d & 7) << 3))] = f2b(acc[m][n][r]);
        }
      }
    __syncthreads();   // block-uniform (bx 20..23 -> heads 40..47 all V)
    const int bb = row0 >> 11, tt0 = row0 & 2047;   // 64-row tile never crosses b
    #pragma unroll
    for (int it = 0; it < 8; ++it) {
      const int d = it * 8 + (lane >> 3);
      const int toff = (lane & 7) * 8;         // u16 units, 16B chunk
      const u32x4 v = *(const u32x4*)&Lw[d * 64 + (toff ^ ((d & 7) << 3))];
      *(u32x4*)(Vt + (((size_t)bb * 8 + g) * 64 + d) * 2048 + tt0 + toff) = v;
    }
  }
}

// ---------- out-proj GEMM 128x128/BK=64, 512 threads / 8 waves (2x4, 64x32 each) ----
__global__ __launch_bounds__(512, 2) void k_gemmOut(const u16* __restrict__ A,
                                                    const u16* __restrict__ Bt,
                                                    float* __restrict__ C,
                                                    int N, int K, int GY) {
  __shared__ u16 lds[16384];                    // 32 KB
  char* const L = (char*)&lds[0];
  const int tid = threadIdx.x;
  const int q8 = gridDim.x >> 3;                // 512 % 8 == 0 (bijective)
  const int id2 = (blockIdx.x & 7) * q8 + (blockIdx.x >> 3);
  const int by = id2 % GY, bx = id2 / GY;
  const int wid = tid >> 6, lane = tid & 63;
  const int wm = wid >> 2, wn = wid & 3;        // 2 x 4 waves, 64x32 C each
  const int l16 = lane & 15, l4 = lane >> 4;
  const size_t K2 = (size_t)K * 2;
  const char* Ab = (const char*)(A + (size_t)(by * 128) * K);
  const char* Bb = (const char*)(Bt + (size_t)(bx * 128) * K);
  const int NT = K >> 6;

  auto stage = [&](const char* gb, int reg, int t) {
    #pragma unroll
    for (int rd = 0; rd < 2; ++rd) {
      const int p = rd * 8192 + tid * 16;       // 0..16383
      const int r = p >> 7;                     // 0..127
      const int cb = (p & 127) ^ ((r & 7) << 4);
      gll16(gb + (size_t)r * K2 + (size_t)t * 128 + cb, L + reg + p);
    }
  };

  const int swz = (l16 & 7) << 4;
  const int c0 = (l4 * 16) ^ swz;               // k-half 0
  const int c1 = (64 + l4 * 16) ^ swz;          // k-half 1
  const int aOff = (wm * 64 + l16) * 128;
  const int bOff = 16384 + (wn * 32 + l16) * 128;

  f32x4 acc[4][2];
  #pragma unroll
  for (int m = 0; m < 4; ++m)
    #pragma unroll
    for (int n = 0; n < 2; ++n) acc[m][n] = f32x4{0.f, 0.f, 0.f, 0.f};

  for (int t = 0; t < NT; ++t) {
    stage(Ab, 0, t);
    stage(Bb, 16384, t);
    __syncthreads();
    sfrag a0[4], a1[4], b0[2], b1[2];
    #pragma unroll
    for (int m = 0; m < 4; ++m) {
      a0[m] = *(const sfrag*)(L + aOff + m * 2048 + c0);
      a1[m] = *(const sfrag*)(L + aOff + m * 2048 + c1);
    }
    #pragma unroll
    for (int n = 0; n < 2; ++n) {
      b0[n] = *(const sfrag*)(L + bOff + n * 2048 + c0);
      b1[n] = *(const sfrag*)(L + bOff + n * 2048 + c1);
    }
    #pragma unroll
    for (int m = 0; m < 4; ++m)
      #pragma unroll
      for (int n = 0; n < 2; ++n) {
        acc[m][n] = mfma16(a0[m], b0[n], acc[m][n]);
        acc[m][n] = mfma16(a1[m], b1[n], acc[m][n]);
      }
    __syncthreads();
  }

  float* Cb = C + (size_t)(by * 128 + wm * 64) * N + bx * 128 + wn * 32;
  #pragma unroll
  for (int m = 0; m < 4; ++m)
    #pragma unroll
    for (int n = 0; n < 2; ++n)
      #pragma unroll
      for (int r = 0; r < 4; ++r)
        Cb[(size_t)(m * 16 + l4 * 4 + r) * N + n * 16 + l16] = acc[m][n][r];
}

// ---------- Flash attention v7: attn5 shell, 64 q-rows per wave ----------
__device__ __forceinline__ void pv4(const float* p, sfrag v0a, sfrag v0b,
                                    sfrag v1a, sfrag v1b,
                                    f32x16& O0, f32x16& O1, float& l) {
  unsigned w[8];
  #pragma unroll
  for (int j = 0; j < 8; ++j) w[j] = pack2(p[2 * j], p[2 * j + 1]);
  swap32(w[0], w[2]);
  swap32(w[1], w[3]);
  swap32(w[4], w[6]);
  swap32(w[5], w[7]);
  const sfrag pf0 = __builtin_bit_cast(sfrag, u32x4{w[0], w[1], w[2], w[3]});
  const sfrag pf1 = __builtin_bit_cast(sfrag, u32x4{w[4], w[5], w[6], w[7]});
  O0 = mfma32(v0a, pf0, O0);
  O0 = mfma32(v0b, pf1, O0);
  O1 = mfma32(v1a, pf0, O1);
  O1 = mfma32(v1b, pf1, O1);
  float s[8];
  #pragma unroll
  for (int j = 0; j < 8; ++j) s[j] = p[j] + p[j + 8];
  #pragma unroll
  for (int j = 0; j < 4; ++j) s[j] = s[j] + s[j + 4];
  l += (s[0] + s[1]) + (s[2] + s[3]);
}

__device__ __forceinline__ void tile64_l(const u16* __restrict__ buf,
                                         const sfrag* qf, int hi, int l31, int swz,
                                         f32x16& O0, f32x16& O1, float& l) {
  const char* Kl = (const char*)buf;
  const char* Vl = Kl + 8192;
  const int rb = l31 * 128;
  f32x16 Sa = {}, Sb = {};
  #pragma unroll
  for (int ks = 0; ks < 4; ++ks) {
    const int col = (hi * 16 + ks * 32) ^ swz;
    const sfrag ka = *(const sfrag*)(Kl + rb + col);
    const sfrag kb = *(const sfrag*)(Kl + rb + col + 4096);
    Sa = mfma32(ka, qf[ks], Sa);
    Sb = mfma32(kb, qf[ks], Sb);
  }
  float pa[16], pb[16];
  #pragma unroll
  for (int r = 0; r < 16; ++r) {
    pa[r] = __builtin_amdgcn_exp2f(Sa[r]);
    pb[r] = __builtin_amdgcn_exp2f(Sb[r]);
  }
  sfrag v0[4], v1[4];
  #pragma unroll
  for (int s = 0; s < 4; ++s) {
    const int col = (s * 32 + hi * 16) ^ swz;
    v0[s] = *(const sfrag*)(Vl + rb + col);
    v1[s] = *(const sfrag*)(Vl + rb + col + 4096);
  }
  pv4(pa, v0[0], v0[1], v1[0], v1[1], O0, O1, l);
  pv4(pb, v0[2], v0[3], v1[2], v1[3], O0, O1, l);
}

template<bool MASKED>
__device__ __forceinline__ void tile32_l(const u16* __restrict__ buf, int c,
                                         const sfrag* qf, int hi, int l31, int swz,
                                         f32x16& O0, f32x16& O1, float& l) {
  const char* Kl = (const char*)buf;
  const char* Vl = Kl + 8192;
  const int rb = l31 * 128;
  f32x16 S = {};
  #pragma unroll
  for (int ks = 0; ks < 4; ++ks) {
    const int col = (hi * 16 + ks * 32) ^ swz;
    const sfrag k = *(const sfrag*)(Kl + c * 4096 + rb + col);
    S = mfma32(k, qf[ks], S);
  }
  float p[16];
  #pragma unroll
  for (int r = 0; r < 16; ++r) {
    float s = S[r];
    if (MASKED) {
      int kvo = (r & 3) + 8 * (r >> 2) + 4 * hi;
      if (kvo > l31) s = -__builtin_inff();
    }
    p[r] = __builtin_amdgcn_exp2f(s);
  }
  const int colA = (c * 64 + hi * 16) ^ swz;
  const int colB = (c * 64 + 32 + hi * 16) ^ swz;
  const sfrag v0a = *(const sfrag*)(Vl + rb + colA);
  const sfrag v0b = *(const sfrag*)(Vl + rb + colB);
  const sfrag v1a = *(const sfrag*)(Vl + rb + colA + 4096);
  const sfrag v1b = *(const sfrag*)(Vl + rb + colB + 4096);
  pv4(p, v0a, v0b, v1a, v1b, O0, O1, l);
}

// Block = (qb2, b, g): 4 waves = 4 heads; each wave owns 64 q-rows (two subtiles).
__global__ __launch_bounds__(256, 2) void k_attn7(const u16* __restrict__ Qb,
                                                  const u16* __restrict__ Kb,
                                                  const u16* __restrict__ Vt,
                                                  u16* __restrict__ attOut) {
  __shared__ u16 lds[2][8192];
  const int bid = blockIdx.x;                 // 512 blocks
  const int qb2 = 31 - (bid >> 4);            // heavy q-blocks launch first
  const int bg = bid & 15;
  const int b = bg >> 3, g = bg & 7;
  const int wave = threadIdx.x >> 6, lane = threadIdx.x & 63;
  const int h = g * 4 + wave;
  const int hi = lane >> 5, l31 = lane & 31;
  const int qrow0 = qb2 * 64;                 // this wave: rows qrow0 .. qrow0+63
  const int swz = (l31 & 7) << 4;

  const u16* Qp0 = Qb + (((size_t)b * 32 + h) * 2048 + qrow0 + l31) * 64 + hi * 8;
  sfrag qf0[4], qf1[4];
  #pragma unroll
  for (int ks = 0; ks < 4; ++ks) {
    qf0[ks] = *(const sfrag*)(Qp0 + ks * 16);
    qf1[ks] = *(const sfrag*)(Qp0 + 32 * 64 + ks * 16);
  }

  const char* Kg = (const char*)(Kb + ((size_t)b * 8 + g) * (2048 * 64));
  const char* Vg = (const char*)(Vt + ((size_t)b * 8 + g) * (64 * 2048));

  auto stage = [&](int bufi, int t) {
    const char* Ktile = Kg + (size_t)t * 8192;
    const char* Vtile = Vg + t * 128;
    #pragma unroll
    for (int rd = 0; rd < 2; ++rd) {
      const int p = rd * 4096 + threadIdx.x * 16;
      const int d = p >> 7;
      const int cb = (p & 127) ^ ((d & 7) << 4);
      const int lbase = rd * 4096 + wave * 1024;
      gll16(Ktile + d * 128 + cb, (char*)&lds[bufi][0] + lbase);
      gll16(Vtile + (size_t)d * 4096 + cb, (char*)&lds[bufi][0] + 8192 + lbase);
    }
  };

  f32x16 O00 = {}, O01 = {}, O10 = {}, O11 = {};
  float ls0 = 0.f, ls1 = 0.f;
  const int nfull = qb2;
  int cur = 0;
  stage(0, 0);
  for (int t = 0; t < nfull; ++t) {
    __syncthreads();
    stage(cur ^ 1, t + 1);
    tile64_l(lds[cur], qf0, hi, l31, swz, O00, O01, ls0);
    tile64_l(lds[cur], qf1, hi, l31, swz, O10, O11, ls1);
    cur ^= 1;
  }
  __syncthreads();
  tile32_l<true >(lds[cur], 0, qf0, hi, l31, swz, O00, O01, ls0);
  tile32_l<false>(lds[cur], 0, qf1, hi, l31, swz, O10, O11, ls1);
  tile32_l<true >(lds[cur], 1, qf1, hi, l31, swz, O10, O11, ls1);

  #pragma unroll
  for (int sb = 0; sb < 2; ++sb) {
    const float lsum = sb ? ls1 : ls0;
    const float ltot = lsum + __shfl_xor(lsum, 32);
    const float inv = 1.0f / ltot;
    const size_t orow = ((size_t)b * 2048 + qrow0 + sb * 32 + l31) * 2048 + h * 64;
    #pragma unroll
    for (int dt = 0; dt < 2; ++dt) {
      const f32x16& O = sb ? (dt ? O11 : O10) : (dt ? O01 : O00);
      #pragma unroll
      for (int k = 0; k < 4; ++k) {
        ushort4 o;
        o.x = f2b(O[4 * k + 0] * inv);
        o.y = f2b(O[4 * k + 1] * inv);
        o.z = f2b(O[4 * k + 2] * inv);
        o.w = f2b(O[4 * k + 3] * inv);
        *(ushort4*)&attOut[orow + dt * 32 + 8 * k + 4 * hi] = o;
      }
    }
  }
}

extern "C" void kernel_launch(void* const* d_in, const int* in_sizes, int n_in,
                              void* d_out, int out_size, void* d_ws, size_t ws_size,
                              hipStream_t stream) {
  const float* x  = (const float*)d_in[0];
  const float* Wq = (const float*)d_in[1];
  const float* Wk = (const float*)d_in[2];
  const float* Wv = (const float*)d_in[3];
  const float* Wo = (const float*)d_in[4];
  const int* sp   = (const int*)d_in[5];
  float* y    = (float*)d_out;            // (B,T,2048) f32
  float* Kout = y + 8388608;              // (B,G,T,64) f32
  float* Vout = y + 10485760;             // (B,G,T,64) f32

  char* ws = (char*)d_ws;
  u16*    xb     = (u16*)(ws + 0);          // 16 MiB (reused as attOut later)
  u16*    Wqkvt  = (u16*)(ws + 16777216);   // 12 MiB  (3072 x 2048 bf16, transposed)
  u16*    Wot    = (u16*)(ws + 29360128);   // 8 MiB
  float2* csn    = (float2*)(ws + 37748736);// 512 KiB (2048 x 32 cos/sin)
  u16*    Qbuf   = (u16*)(ws + 88080384);   // 16 MiB  (B,H,T,hd) bf16, pre-scaled
  u16*    Kbuf   = (u16*)(ws + 104857600);  // 4 MiB   (B,G,T,hd) bf16
  u16*    Vt     = (u16*)(ws + 109051904);  // 4 MiB   (B,G,hd,T) bf16
  u16*    attOut = xb;                      // alias: xb dead after QKV GEMM

  k_prep<<<11008, 256, 0, stream>>>(x, xb, sp, csn, Wq, Wk, Wv, Wo, Wqkvt, Wot);
  k_gemmQKV<<<768, 256, 0, stream>>>(xb, Wqkvt, 2048, 32, csn, Qbuf, Kbuf,
                                     Kout, Vout, Vt);
  k_attn7<<<512, 256, 0, stream>>>(Qbuf, Kbuf, Vt, attOut);
  k_gemmOut<<<512, 512, 0, stream>>>(attOut, Wot, y, 2048, 2048, 32);
}